// Round 2
// baseline (4459.787 us; speedup 1.0000x reference)
//
#include <hip/hip_runtime.h>

#define NB   262144
#define NCH  29

typedef __bf16 bf16x8 __attribute__((ext_vector_type(8)));
typedef float  f32x4  __attribute__((ext_vector_type(4)));

__device__ __forceinline__ float elu_f(float x) {
    return x > 0.0f ? x : (__expf(x) - 1.0f);
}
__device__ __forceinline__ float softplus_f(float x) {
    return fmaxf(x, 0.0f) + __logf(1.0f + __expf(-fabsf(x)));
}

// Block: 256 threads = 4 waves, 128 samples, one channel k.
// Phase p=0 (mu/direct), p=1 (mu_bar/diffuse): layer1 in-lane (f32 VALU),
// layer2 = 16x16x32 bf16 MFMA with hi/lo split (3 MFMA per tile, ~f32 acc),
// ELU'd h2 -> LDS bf16 [256 rows][72], then 1 thread = 1 (sample, mlp) row
// for layer3 + softplus/softmax/transmittance.
__global__ __launch_bounds__(256, 3)
void lp_kernel(const float* __restrict__ tg, const float* __restrict__ tl,
               const float* __restrict__ ti, const float* __restrict__ mu,
               const float* __restrict__ mub,
               const float* __restrict__ W1, const float* __restrict__ B1,
               const float* __restrict__ W2, const float* __restrict__ B2,
               const float* __restrict__ W3, const float* __restrict__ B3,
               float* __restrict__ out)
{
    __shared__ unsigned short h2e[256 * 72];   // 36.9 KB, stride 72 (144 B, 16B-aligned)

    const int tid  = threadIdx.x;
    const int lane = tid & 63;
    const int wv   = tid >> 6;         // wave 0..3
    const int r16  = lane & 15;        // MFMA row / col index
    const int kg   = lane >> 4;        // k-slice group 0..3

    // XCD-grouped mapping: blocks with the same sample-range land on one XCD
    // (tau line reuse in its L2); 8 * 256 * 29 = 59392 blocks.
    const int bid  = blockIdx.x;
    const int xcd  = bid & 7;
    const int slot = bid >> 3;          // 0..7423
    const int k    = slot % NCH;
    const int sbr  = slot / NCH;        // 0..255
    const int base = ((xcd << 8) | sbr) * 128;   // first sample of this block

    const float* __restrict__ w1p = W1 + k * 256;   // [4][64]
    const float* __restrict__ b1p = B1 + k * 64;
    const float* __restrict__ w2p = W2 + k * 4096;  // [64][64]
    const float* __restrict__ b2p = B2 + k * 64;
    const float* __restrict__ w3p = W3 + k * 192;   // [64][3]
    const float* __restrict__ b3p = B3 + k * 3;

    // ---- B fragments: W2 hi/lo. lane holds n = r16+16*nt, k = ks*32+kg*8+e.
    bf16x8 bhi[4][2], blo[4][2];
#pragma unroll
    for (int nt = 0; nt < 4; ++nt) {
#pragma unroll
      for (int ks = 0; ks < 2; ++ks) {
        const int kb = ks * 32 + kg * 8;
        const int cn = r16 + nt * 16;
#pragma unroll
        for (int e = 0; e < 8; ++e) {
          const float w  = w2p[(kb + e) * 64 + cn];
          const __bf16 wh = (__bf16)w;             // RNE
          bhi[nt][ks][e] = wh;
          blo[nt][ks][e] = (__bf16)(w - (float)wh); // exact remainder, RNE to bf16
        }
      }
    }

    float b2c[4];
#pragma unroll
    for (int nt = 0; nt < 4; ++nt) b2c[nt] = b2p[r16 + nt * 16];

    // ---- GEMM phases (p=0 direct, p=1 diffuse)
#pragma unroll
    for (int p = 0; p < 2; ++p) {
      const float* __restrict__ msel = p ? mub : mu;
#pragma unroll
      for (int mt = 0; mt < 2; ++mt) {
        const int Rb   = wv * 32 + mt * 16;        // phase-local row base
        const int s    = base + Rb + r16;          // this lane's A-row sample
        const int sidx = s * NCH + k;
        const float x0 = tg[sidx], x1 = tl[sidx], x2 = ti[sidx];
        const float x3 = msel[s];

        // A fragments: h1 = elu(x . W1 + b1), lane owns row r16, k-slice kg*8.
        bf16x8 ahi[2], alo[2];
#pragma unroll
        for (int ks = 0; ks < 2; ++ks) {
          const int jb = ks * 32 + kg * 8;
#pragma unroll
          for (int e = 0; e < 8; ++e) {
            const int j = jb + e;
            float h = b1p[j];
            h = fmaf(x0, w1p[j],       h);
            h = fmaf(x1, w1p[64 + j],  h);
            h = fmaf(x2, w1p[128 + j], h);
            h = fmaf(x3, w1p[192 + j], h);
            h = elu_f(h);
            const __bf16 hb = (__bf16)h;
            ahi[ks][e] = hb;
            alo[ks][e] = (__bf16)(h - (float)hb);
          }
        }

#pragma unroll
        for (int nt = 0; nt < 4; ++nt) {
          f32x4 acc = { b2c[nt], b2c[nt], b2c[nt], b2c[nt] };  // bias pre-init
#pragma unroll
          for (int ks = 0; ks < 2; ++ks) {
            acc = __builtin_amdgcn_mfma_f32_16x16x32_bf16(ahi[ks], bhi[nt][ks], acc, 0, 0, 0);
            acc = __builtin_amdgcn_mfma_f32_16x16x32_bf16(alo[ks], bhi[nt][ks], acc, 0, 0, 0);
            acc = __builtin_amdgcn_mfma_f32_16x16x32_bf16(ahi[ks], blo[nt][ks], acc, 0, 0, 0);
          }
          // C/D: col = lane&15 (+16*nt), row = (lane>>4)*4 + reg  [m89-verified]
          const int colg = r16 + nt * 16;
          const int row0 = p * 128 + Rb + kg * 4;
#pragma unroll
          for (int rr = 0; rr < 4; ++rr) {
            const float v = elu_f(acc[rr]);
            h2e[(row0 + rr) * 72 + colg] = __builtin_bit_cast(unsigned short, (__bf16)v);
          }
        }
      }
    }

    __syncthreads();

    // ---- Layer 3 + epilogue: thread = one (sample, mlp-instance) row.
    {
      const int p2   = tid >> 7;          // 0 = direct, 1 = diffuse
      const int r    = tid & 127;
      const int s    = base + r;
      const int sidx = s * NCH + k;

      const uint4* __restrict__ rowp = (const uint4*)&h2e[tid * 72];
      float o0 = b3p[0], o1 = b3p[1], o2 = b3p[2];

#define ACC_PAIR(uw, g0) {                                                        \
        const float fe = __builtin_bit_cast(float, (unsigned int)((uw) << 16));   \
        const float fo = __builtin_bit_cast(float, (uw) & 0xffff0000u);           \
        o0 = fmaf(fe, w3p[(g0) * 3 + 0], o0);                                     \
        o1 = fmaf(fe, w3p[(g0) * 3 + 1], o1);                                     \
        o2 = fmaf(fe, w3p[(g0) * 3 + 2], o2);                                     \
        o0 = fmaf(fo, w3p[(g0 + 1) * 3 + 0], o0);                                 \
        o1 = fmaf(fo, w3p[(g0 + 1) * 3 + 1], o1);                                 \
        o2 = fmaf(fo, w3p[(g0 + 1) * 3 + 2], o2); }

#pragma unroll
      for (int jb = 0; jb < 8; ++jb) {
        const uint4 u = rowp[jb];
        ACC_PAIR(u.x, jb * 8 + 0)
        ACC_PAIR(u.y, jb * 8 + 2)
        ACC_PAIR(u.z, jb * 8 + 4)
        ACC_PAIR(u.w, jb * 8 + 6)
      }
#undef ACC_PAIR

      float s0 = softplus_f(o0), s1 = softplus_f(o1), s2 = softplus_f(o2);
      const float mx = fmaxf(s0, fmaxf(s1, s2));
      const float e0 = __expf(s0 - mx), e1 = __expf(s1 - mx), e2 = __expf(s2 - mx);
      const float rs = 1.0f / (e0 + e1 + e2);

      const float m   = p2 ? mub[s] : mu[s];
      const float eps = p2 ? 1e-3f : 1e-5f;
      const float tt  = __expf(-(tg[sidx] + tl[sidx] + ti[sidx]) / (m + eps));

      float* o8 = out + (size_t)sidx * 8;
      o8[p2]            = tt;
      o8[2 + 3 * p2 + 0] = e0 * rs;
      o8[2 + 3 * p2 + 1] = e1 * rs;
      o8[2 + 3 * p2 + 2] = e2 * rs;
    }
}

extern "C" void kernel_launch(void* const* d_in, const int* in_sizes, int n_in,
                              void* d_out, int out_size, void* d_ws, size_t ws_size,
                              hipStream_t stream) {
    const float* tg  = (const float*)d_in[0];
    const float* tl  = (const float*)d_in[1];
    const float* ti  = (const float*)d_in[2];
    const float* mu  = (const float*)d_in[3];
    const float* mub = (const float*)d_in[4];
    const float* W1  = (const float*)d_in[5];
    const float* B1  = (const float*)d_in[6];
    const float* W2  = (const float*)d_in[7];
    const float* B2  = (const float*)d_in[8];
    const float* W3  = (const float*)d_in[9];
    const float* B3  = (const float*)d_in[10];
    float* out = (float*)d_out;

    const int nblk = 8 * 256 * NCH;   // 59392 blocks x 256 threads = 128 samples/block
    lp_kernel<<<dim3(nblk), dim3(256), 0, stream>>>(tg, tl, ti, mu, mub,
                                                    W1, B1, W2, B2, W3, B3, out);
}

// Round 3
// 988.689 us; speedup vs baseline: 4.5108x; 4.5108x over previous
//
#include <hip/hip_runtime.h>

#define NB   262144
#define NCH  29

typedef __bf16 bf16x8 __attribute__((ext_vector_type(8)));
typedef float  f32x4  __attribute__((ext_vector_type(4)));

__device__ __forceinline__ float elu_f(float x) {
    return x > 0.0f ? x : (__expf(x) - 1.0f);
}
__device__ __forceinline__ float softplus_f(float x) {
    return fmaxf(x, 0.0f) + __logf(1.0f + __expf(-fabsf(x)));
}

// ---------------------------------------------------------------------------
// Prep: split W2 into hi/lo bf16, laid out in exact MFMA-lane fragment order:
// index = ((((k*2+ks)*4+kg)*64)+n)*8+e  ==  gid bit layout below.
// ---------------------------------------------------------------------------
__global__ void w2_prep(const float* __restrict__ W2,
                        __bf16* __restrict__ whi, __bf16* __restrict__ wlo) {
    const int gid = blockIdx.x * 256 + threadIdx.x;      // < 475136
    const int e  = gid & 7;
    const int n  = (gid >> 3) & 63;
    const int kg = (gid >> 9) & 3;
    const int ks = (gid >> 11) & 1;
    const int k  = gid >> 12;                            // < 29
    const float w  = W2[k * 4096 + (ks * 32 + kg * 8 + e) * 64 + n];
    const __bf16 h = (__bf16)w;
    whi[gid] = h;
    wlo[gid] = (__bf16)(w - (float)h);
}

// ---------------------------------------------------------------------------
// Main: block = 256 threads (4 waves) x 128 samples x 1 channel.
// Layer1 in-lane (both phases share the tau part), layer2 = bf16 hi/lo MFMA,
// h2(bf16) -> LDS, layer3 + softplus/softmax per (sample,phase) row,
// full-32B output stores from the p2=0 threads via an LDS exchange.
// ---------------------------------------------------------------------------
__global__ __launch_bounds__(256, 3)
void lp_kernel(const float* __restrict__ tg, const float* __restrict__ tl,
               const float* __restrict__ ti, const float* __restrict__ mu,
               const float* __restrict__ mub,
               const float* __restrict__ W1, const float* __restrict__ B1,
               const float* __restrict__ W2, const float* __restrict__ B2,
               const float* __restrict__ W3, const float* __restrict__ B3,
               const __bf16* __restrict__ whi, const __bf16* __restrict__ wlo,
               const int use_ws,
               float* __restrict__ out)
{
    __shared__ __align__(16) unsigned short h2e[256 * 72];  // 36.9 KB
    __shared__ __align__(16) float4 w1a[72];                // padded-index W1^T
    __shared__ float  b1l[64];
    __shared__ __align__(16) float xs[128][8];              // x0,x1,x2,mu,mub,td,tf
    __shared__ __align__(16) float ex[128][4];              // diffuse exchange

    const int tid  = threadIdx.x;
    const int lane = tid & 63;
    const int wv   = tid >> 6;
    const int r16  = lane & 15;
    const int kg   = lane >> 4;

    const int bid  = blockIdx.x;
    const int xcd  = bid & 7;
    const int slot = bid >> 3;               // 0..7423
    const int k    = slot % NCH;
    const int sbr  = slot / NCH;             // 0..255
    const int base = ((xcd << 8) | sbr) * 128;

    const float* __restrict__ w1p = W1 + k * 256;
    const float* __restrict__ b1p = B1 + k * 64;
    const float* __restrict__ b2p = B2 + k * 64;
    const float* __restrict__ w3p = W3 + k * 192;
    const float* __restrict__ b3p = B3 + k * 3;

    // ---- stage tau/mu (+ transmittances) and W1^T into LDS
    if (tid < 128) {
        const int s = base + tid, sidx = s * NCH + k;
        const float x0 = tg[sidx], x1 = tl[sidx], x2 = ti[sidx];
        const float m = mu[s], mb = mub[s];
        xs[tid][0] = x0; xs[tid][1] = x1; xs[tid][2] = x2;
        xs[tid][3] = m;  xs[tid][4] = mb;
        const float tt = x0 + x1 + x2;
        xs[tid][5] = __expf(-tt / (m + 1e-5f));
        xs[tid][6] = __expf(-tt / (mb + 1e-3f));
    }
    if (tid < 64) {
        const int p = tid + (tid >> 3);      // bank-spread index
        w1a[p] = make_float4(w1p[tid], w1p[64 + tid], w1p[128 + tid], w1p[192 + tid]);
        b1l[tid] = b1p[tid];
    }

    // ---- B fragments (registers): pre-split path or in-kernel split
    bf16x8 bh[4][2], bl[4][2];
    if (use_ws) {
        const bf16x8* __restrict__ hp =
            (const bf16x8*)(whi + (size_t)k * 2 * 4 * 64 * 8);
        const bf16x8* __restrict__ lp =
            (const bf16x8*)(wlo + (size_t)k * 2 * 4 * 64 * 8);
#pragma unroll
        for (int ks = 0; ks < 2; ++ks)
#pragma unroll
            for (int nt = 0; nt < 4; ++nt) {
                const int off = (ks * 4 + kg) * 64 + r16 + 16 * nt;
                bh[nt][ks] = hp[off];
                bl[nt][ks] = lp[off];
            }
    } else {
        const float* __restrict__ w2p = W2 + k * 4096;
#pragma unroll
        for (int nt = 0; nt < 4; ++nt)
#pragma unroll
            for (int ks = 0; ks < 2; ++ks) {
                const int kb = ks * 32 + kg * 8;
                const int cn = r16 + nt * 16;
#pragma unroll
                for (int e = 0; e < 8; ++e) {
                    const float w  = w2p[(kb + e) * 64 + cn];
                    const __bf16 h = (__bf16)w;
                    bh[nt][ks][e] = h;
                    bl[nt][ks][e] = (__bf16)(w - (float)h);
                }
            }
    }

    float b2c[4];
#pragma unroll
    for (int nt = 0; nt < 4; ++nt) b2c[nt] = b2p[r16 + nt * 16];

    __syncthreads();

    // ---- main: 2 M-tiles per wave, both phases fused
#pragma unroll
    for (int mt = 0; mt < 2; ++mt) {
        const int Rb = wv * 32 + mt * 16;
        const int r  = Rb + r16;
        const float4 xv = *(const float4*)&xs[r][0];   // x0,x1,x2,mu
        const float  mb = xs[r][4];

        bf16x8 Ahd[2], Ald[2], Ahf[2], Alf[2];
#pragma unroll
        for (int ks = 0; ks < 2; ++ks) {
#pragma unroll
            for (int e = 0; e < 8; ++e) {
                const int j  = ks * 32 + kg * 8 + e;
                const int pj = j + (j >> 3);
                const float4 wj = w1a[pj];
                float a = b1l[j];
                a = fmaf(xv.x, wj.x, a);
                a = fmaf(xv.y, wj.y, a);
                a = fmaf(xv.z, wj.z, a);
                const float hd = elu_f(fmaf(xv.w, wj.w, a));
                const float hf = elu_f(fmaf(mb,   wj.w, a));
                const __bf16 hdh = (__bf16)hd;
                Ahd[ks][e] = hdh; Ald[ks][e] = (__bf16)(hd - (float)hdh);
                const __bf16 hfh = (__bf16)hf;
                Ahf[ks][e] = hfh; Alf[ks][e] = (__bf16)(hf - (float)hfh);
            }
        }

#pragma unroll
        for (int nt = 0; nt < 4; ++nt) {
            f32x4 ad = { b2c[nt], b2c[nt], b2c[nt], b2c[nt] };
            f32x4 af = ad;
#pragma unroll
            for (int ks = 0; ks < 2; ++ks) {
                ad = __builtin_amdgcn_mfma_f32_16x16x32_bf16(Ahd[ks], bh[nt][ks], ad, 0, 0, 0);
                ad = __builtin_amdgcn_mfma_f32_16x16x32_bf16(Ald[ks], bh[nt][ks], ad, 0, 0, 0);
                ad = __builtin_amdgcn_mfma_f32_16x16x32_bf16(Ahd[ks], bl[nt][ks], ad, 0, 0, 0);
                af = __builtin_amdgcn_mfma_f32_16x16x32_bf16(Ahf[ks], bh[nt][ks], af, 0, 0, 0);
                af = __builtin_amdgcn_mfma_f32_16x16x32_bf16(Alf[ks], bh[nt][ks], af, 0, 0, 0);
                af = __builtin_amdgcn_mfma_f32_16x16x32_bf16(Ahf[ks], bl[nt][ks], af, 0, 0, 0);
            }
            const int colg = r16 + 16 * nt;
            const int r0d  = (Rb + kg * 4) * 72 + colg;
            const int r0f  = (128 + Rb + kg * 4) * 72 + colg;
#pragma unroll
            for (int rr = 0; rr < 4; ++rr) {
                h2e[r0d + rr * 72] = __builtin_bit_cast(unsigned short, (__bf16)elu_f(ad[rr]));
                h2e[r0f + rr * 72] = __builtin_bit_cast(unsigned short, (__bf16)elu_f(af[rr]));
            }
        }
    }

    __syncthreads();

    // ---- layer 3 + softplus/softmax: thread = one (sample, phase) row
    const uint4* __restrict__ rowp = (const uint4*)&h2e[tid * 72];
    float o0 = b3p[0], o1 = b3p[1], o2 = b3p[2];

#define ACC_PAIR(uw, g0) {                                                        \
        const float fe = __builtin_bit_cast(float, (unsigned int)((uw) << 16));   \
        const float fo = __builtin_bit_cast(float, (uw) & 0xffff0000u);           \
        o0 = fmaf(fe, w3p[(g0) * 3 + 0], o0);                                     \
        o1 = fmaf(fe, w3p[(g0) * 3 + 1], o1);                                     \
        o2 = fmaf(fe, w3p[(g0) * 3 + 2], o2);                                     \
        o0 = fmaf(fo, w3p[(g0 + 1) * 3 + 0], o0);                                 \
        o1 = fmaf(fo, w3p[(g0 + 1) * 3 + 1], o1);                                 \
        o2 = fmaf(fo, w3p[(g0 + 1) * 3 + 2], o2); }

#pragma unroll
    for (int jb = 0; jb < 8; ++jb) {
        const uint4 u = rowp[jb];
        ACC_PAIR(u.x, jb * 8 + 0)
        ACC_PAIR(u.y, jb * 8 + 2)
        ACC_PAIR(u.z, jb * 8 + 4)
        ACC_PAIR(u.w, jb * 8 + 6)
    }
#undef ACC_PAIR

    float s0 = softplus_f(o0), s1 = softplus_f(o1), s2 = softplus_f(o2);
    const float mx = fmaxf(s0, fmaxf(s1, s2));
    const float e0 = __expf(s0 - mx), e1 = __expf(s1 - mx), e2 = __expf(s2 - mx);
    const float rs = 1.0f / (e0 + e1 + e2);

    const int r = tid & 127;
    if (tid >= 128) {                 // diffuse rows publish to LDS
        ex[r][0] = e0 * rs; ex[r][1] = e1 * rs; ex[r][2] = e2 * rs;
    }
    __syncthreads();
    if (tid < 128) {                  // direct rows write the full 32B line
        const int s = base + r, sidx = s * NCH + k;
        float4 oa = make_float4(xs[r][5], xs[r][6], e0 * rs, e1 * rs);
        float4 ob = make_float4(e2 * rs, ex[r][0], ex[r][1], ex[r][2]);
        float4* op = (float4*)(out + (size_t)sidx * 8);
        op[0] = oa;
        op[1] = ob;
    }
}

extern "C" void kernel_launch(void* const* d_in, const int* in_sizes, int n_in,
                              void* d_out, int out_size, void* d_ws, size_t ws_size,
                              hipStream_t stream) {
    const float* tg  = (const float*)d_in[0];
    const float* tl  = (const float*)d_in[1];
    const float* ti  = (const float*)d_in[2];
    const float* mu  = (const float*)d_in[3];
    const float* mub = (const float*)d_in[4];
    const float* W1  = (const float*)d_in[5];
    const float* B1  = (const float*)d_in[6];
    const float* W2  = (const float*)d_in[7];
    const float* B2  = (const float*)d_in[8];
    const float* W3  = (const float*)d_in[9];
    const float* B3  = (const float*)d_in[10];
    float* out = (float*)d_out;

    const int nfrag = NCH * 2 * 4 * 64 * 8;            // 475136
    const int use_ws = (ws_size >= (size_t)(2 * nfrag * 2)) ? 1 : 0;
    __bf16* whi = (__bf16*)d_ws;
    __bf16* wlo = whi + nfrag;

    if (use_ws) {
        w2_prep<<<dim3(nfrag / 256), dim3(256), 0, stream>>>(W2, whi, wlo);
    }
    const int nblk = 8 * 256 * NCH;                    // 59392
    lp_kernel<<<dim3(nblk), dim3(256), 0, stream>>>(tg, tl, ti, mu, mub,
                                                    W1, B1, W2, B2, W3, B3,
                                                    whi, wlo, use_ws, out);
}